// Round 1
// baseline (5667.060 us; speedup 1.0000x reference)
//
#include <hip/hip_runtime.h>

#define D 128
#define BN_EPS 1e-5f

// -------------------- scatter: agg[row] += x[col] --------------------
// 32 lanes per edge, float4 per lane (128 floats/edge), HW f32 atomics.
__global__ __launch_bounds__(256) void scatter_kernel(
    const float* __restrict__ x, const int* __restrict__ ei,
    float* __restrict__ agg, int E) {
  int t = blockIdx.x * blockDim.x + threadIdx.x;
  int edge = t >> 5;
  int lane = t & 31;
  if (edge >= E) return;
  int dst = ei[edge];       // row (segment id)
  int src = ei[E + edge];   // col (neighbor)
  const float4 v = *reinterpret_cast<const float4*>(x + (size_t)src * D + lane * 4);
  float* o = agg + (size_t)dst * D + lane * 4;
  unsafeAtomicAdd(o + 0, v.x);
  unsafeAtomicAdd(o + 1, v.y);
  unsafeAtomicAdd(o + 2, v.z);
  unsafeAtomicAdd(o + 3, v.w);
}

// -------------------- fused 3-way GEMM: pre = x@W1^T + aggL@W2l^T + aggG@W2g^T
// Block: 128 nodes x 128 outs, 256 threads, 8x8 register tile/thread.
__global__ __launch_bounds__(256) void gemm3_kernel(
    const float* __restrict__ x, const float* __restrict__ aggL,
    const float* __restrict__ aggG, const float* __restrict__ W1,
    const float* __restrict__ W2l, const float* __restrict__ W2g,
    float* __restrict__ pre, int n) {
  __shared__ float xs[128][33];  // +1 pad: bank = (row + k) % 32
  __shared__ float ws[128][33];
  const int tid = threadIdx.x;
  const int ty = tid >> 4;       // 0..15 node group
  const int tx = tid & 15;       // 0..15 out group
  const int nodeBase = blockIdx.x * 128;

  float acc[8][8];
#pragma unroll
  for (int i = 0; i < 8; ++i)
#pragma unroll
    for (int j = 0; j < 8; ++j) acc[i][j] = 0.f;

  const float* ins[3] = {x, aggL, aggG};
  const float* wts[3] = {W1, W2l, W2g};

  for (int p = 0; p < 3; ++p) {
    const float* __restrict__ A = ins[p];
    const float* __restrict__ Wp = wts[p];
    for (int kc = 0; kc < D; kc += 32) {
      __syncthreads();  // protect prior-iteration reads
      // load 128x32 input tile and 128x32 weight tile (float4 global loads)
#pragma unroll
      for (int i = 0; i < 4; ++i) {
        int lin = tid + i * 256;     // 0..1023
        int r = lin >> 3;            // 0..127
        int q = lin & 7;             // float4 index within 32 cols
        int node = nodeBase + r;
        float4 v = make_float4(0.f, 0.f, 0.f, 0.f);
        if (node < n)
          v = *reinterpret_cast<const float4*>(A + (size_t)node * D + kc + q * 4);
        xs[r][q * 4 + 0] = v.x; xs[r][q * 4 + 1] = v.y;
        xs[r][q * 4 + 2] = v.z; xs[r][q * 4 + 3] = v.w;
        float4 w = *reinterpret_cast<const float4*>(Wp + (size_t)r * D + kc + q * 4);
        ws[r][q * 4 + 0] = w.x; ws[r][q * 4 + 1] = w.y;
        ws[r][q * 4 + 2] = w.z; ws[r][q * 4 + 3] = w.w;
      }
      __syncthreads();
#pragma unroll
      for (int k = 0; k < 32; ++k) {
        float a[8], b[8];
#pragma unroll
        for (int i = 0; i < 8; ++i) a[i] = xs[ty * 8 + i][k];
#pragma unroll
        for (int j = 0; j < 8; ++j) b[j] = ws[tx * 8 + j][k];
#pragma unroll
        for (int i = 0; i < 8; ++i)
#pragma unroll
          for (int j = 0; j < 8; ++j) acc[i][j] += a[i] * b[j];
      }
    }
  }

#pragma unroll
  for (int i = 0; i < 8; ++i) {
    int node = nodeBase + ty * 8 + i;
    if (node < n) {
      float* row = pre + (size_t)node * D + tx * 8;
      *reinterpret_cast<float4*>(row + 0) = make_float4(acc[i][0], acc[i][1], acc[i][2], acc[i][3]);
      *reinterpret_cast<float4*>(row + 4) = make_float4(acc[i][4], acc[i][5], acc[i][6], acc[i][7]);
    }
  }
}

// -------------------- BN stats: per-feature sum and sumsq --------------------
__global__ __launch_bounds__(256) void stats_kernel(
    const float* __restrict__ pre, float* __restrict__ sums,
    float* __restrict__ sumsq, int n) {
  const int f = threadIdx.x & 127;
  const int g = threadIdx.x >> 7;  // 0/1
  const int base = blockIdx.x * 256;
  float s = 0.f, s2 = 0.f;
  int lim = base + 256 < n ? base + 256 : n;
  for (int r = base + g; r < lim; r += 2) {
    float v = pre[(size_t)r * D + f];
    s += v;
    s2 += v * v;
  }
  __shared__ float bufs[128], bufs2[128];
  if (g) { bufs[f] = s; bufs2[f] = s2; }
  __syncthreads();
  if (!g) {
    unsafeAtomicAdd(&sums[f], s + bufs[f]);
    unsafeAtomicAdd(&sumsq[f], s2 + bufs2[f]);
  }
}

// -------------------- BN params: scale/shift per feature --------------------
__global__ void bnparam_kernel(const float* __restrict__ sums,
                               const float* __restrict__ sumsq,
                               const float* __restrict__ gamma,
                               const float* __restrict__ beta,
                               float* __restrict__ scale,
                               float* __restrict__ shift, int n) {
  int f = threadIdx.x;
  float inv_n = 1.f / (float)n;
  float mean = sums[f] * inv_n;
  float var = sumsq[f] * inv_n - mean * mean;
  float sc = rsqrtf(var + BN_EPS) * gamma[f];
  scale[f] = sc;
  shift[f] = beta[f] - mean * sc;
}

// -------------------- normalize + relu --------------------
__global__ __launch_bounds__(256) void norm_relu_kernel(
    const float* __restrict__ pre, const float* __restrict__ scale,
    const float* __restrict__ shift, float* __restrict__ out, size_t total4) {
  size_t idx = (size_t)blockIdx.x * blockDim.x + threadIdx.x;
  if (idx >= total4) return;
  size_t i = idx * 4;
  float4 v = *reinterpret_cast<const float4*>(pre + i);
  int f = (int)(i & 127);  // feature of first element; 4 consecutive, no row crossing
  v.x = fmaxf(v.x * scale[f + 0] + shift[f + 0], 0.f);
  v.y = fmaxf(v.y * scale[f + 1] + shift[f + 1], 0.f);
  v.z = fmaxf(v.z * scale[f + 2] + shift[f + 2], 0.f);
  v.w = fmaxf(v.w * scale[f + 3] + shift[f + 3], 0.f);
  *reinterpret_cast<float4*>(out + i) = v;
}

extern "C" void kernel_launch(void* const* d_in, const int* in_sizes, int n_in,
                              void* d_out, int out_size, void* d_ws, size_t ws_size,
                              hipStream_t stream) {
  const float* x     = (const float*)d_in[0];
  const int*   eiL   = (const int*)d_in[1];
  const int*   eiG   = (const int*)d_in[2];
  const float* W1    = (const float*)d_in[3];
  const float* W2l   = (const float*)d_in[4];
  const float* W2g   = (const float*)d_in[5];
  const float* gamma = (const float*)d_in[6];
  const float* beta  = (const float*)d_in[7];
  float* out = (float*)d_out;

  const int n = in_sizes[0] / D;        // 50000
  const int E = in_sizes[1] / 2;        // 1600000
  const size_t nd = (size_t)n * D;      // 6.4M

  float* ws    = (float*)d_ws;
  float* aggL  = ws;
  float* aggG  = ws + nd;
  float* pre   = ws + 2 * nd;
  float* sums  = ws + 3 * nd;
  float* sumsq = sums + 128;
  float* scale = sums + 256;
  float* shift = sums + 384;

  // zero the atomic targets (ws is poisoned 0xAA before every launch)
  hipMemsetAsync(aggL, 0, 2 * nd * sizeof(float), stream);
  hipMemsetAsync(sums, 0, 256 * sizeof(float), stream);

  // scatter both edge sets
  {
    long long threads = (long long)E * 32;
    int nblk = (int)((threads + 255) / 256);
    scatter_kernel<<<nblk, 256, 0, stream>>>(x, eiL, aggL, E);
    scatter_kernel<<<nblk, 256, 0, stream>>>(x, eiG, aggG, E);
  }

  // fused 3-way GEMM into pre
  {
    int nblk = (n + 127) / 128;
    gemm3_kernel<<<nblk, 256, 0, stream>>>(x, aggL, aggG, W1, W2l, W2g, pre, n);
  }

  // BN stats + params + normalize
  stats_kernel<<<(n + 255) / 256, 256, 0, stream>>>(pre, sums, sumsq, n);
  bnparam_kernel<<<1, 128, 0, stream>>>(sums, sumsq, gamma, beta, scale, shift, n);
  {
    size_t total4 = nd / 4;
    int nblk = (int)((total4 + 255) / 256);
    norm_relu_kernel<<<nblk, 256, 0, stream>>>(pre, scale, shift, out, total4);
  }
}

// Round 3
// 1059.416 us; speedup vs baseline: 5.3492x; 5.3492x over previous
//
#include <hip/hip_runtime.h>

#define D 128
#define BN_EPS 1e-5f

// -------------------- CSR build: degree histogram --------------------
__global__ __launch_bounds__(256) void hist_kernel(
    const int* __restrict__ ei, int* __restrict__ deg, int E) {
  int t = blockIdx.x * blockDim.x + threadIdx.x;
  if (t < E) atomicAdd(&deg[ei[t]], 1);   // ei[0..E) = dst rows
}

// -------------------- exclusive scan of degrees (single block) --------------------
__global__ __launch_bounds__(1024) void scan_kernel(
    const int* __restrict__ deg, int* __restrict__ off, int n) {
  __shared__ int ls[1024];
  const int t = threadIdx.x;
  const int chunk = (n + 1023) / 1024;
  const int lo = t * chunk;
  const int hi = (lo + chunk < n) ? lo + chunk : n;
  int s = 0;
  for (int j = lo; j < hi; ++j) s += deg[j];
  ls[t] = s;
  __syncthreads();
  // Hillis-Steele inclusive scan over thread sums
  for (int d = 1; d < 1024; d <<= 1) {
    int v = (t >= d) ? ls[t - d] : 0;
    __syncthreads();
    ls[t] += v;
    __syncthreads();
  }
  int run = (t == 0) ? 0 : ls[t - 1];
  for (int j = lo; j < hi; ++j) { off[j] = run; run += deg[j]; }
}

// -------------------- CSR fill: csr[pos++] = src --------------------
// After this kernel, off[i] holds END position of node i's edge list.
__global__ __launch_bounds__(256) void fill_kernel(
    const int* __restrict__ ei, int* __restrict__ off,
    int* __restrict__ csr, int E) {
  int t = blockIdx.x * blockDim.x + threadIdx.x;
  if (t < E) {
    int dst = ei[t];
    int src = ei[E + t];
    int p = atomicAdd(&off[dst], 1);
    csr[p] = src;
  }
}

// -------------------- gather-aggregate: agg[node] = sum x[csr[e]] --------------------
// One wave per node; lane holds features [2*lane, 2*lane+1] in registers.
__global__ __launch_bounds__(256) void gather_kernel(
    const float* __restrict__ x, const int* __restrict__ csr,
    const int* __restrict__ off_end, const int* __restrict__ deg,
    float* __restrict__ agg, int n) {
  const int wid = (blockIdx.x * 256 + threadIdx.x) >> 6;  // node
  const int lane = threadIdx.x & 63;
  if (wid >= n) return;
  const int end = off_end[wid];
  const int beg = end - deg[wid];
  const float* xb = x + lane * 2;
  float ax = 0.f, ay = 0.f;
  int e = beg;
  for (; e + 4 <= end; e += 4) {
    int s0 = csr[e], s1 = csr[e + 1], s2 = csr[e + 2], s3 = csr[e + 3];
    float2 v0 = *reinterpret_cast<const float2*>(xb + (size_t)s0 * D);
    float2 v1 = *reinterpret_cast<const float2*>(xb + (size_t)s1 * D);
    float2 v2 = *reinterpret_cast<const float2*>(xb + (size_t)s2 * D);
    float2 v3 = *reinterpret_cast<const float2*>(xb + (size_t)s3 * D);
    ax += v0.x + v1.x + v2.x + v3.x;
    ay += v0.y + v1.y + v2.y + v3.y;
  }
  for (; e < end; ++e) {
    float2 v = *reinterpret_cast<const float2*>(xb + (size_t)csr[e] * D);
    ax += v.x; ay += v.y;
  }
  *reinterpret_cast<float2*>(agg + (size_t)wid * D + lane * 2) = make_float2(ax, ay);
}

// -------------------- fused 3-way GEMM: pre = x@W1^T + aggL@W2l^T + aggG@W2g^T
__global__ __launch_bounds__(256) void gemm3_kernel(
    const float* __restrict__ x, const float* __restrict__ aggL,
    const float* __restrict__ aggG, const float* __restrict__ W1,
    const float* __restrict__ W2l, const float* __restrict__ W2g,
    float* __restrict__ pre, int n) {
  __shared__ float xs[128][33];
  __shared__ float ws[128][33];
  const int tid = threadIdx.x;
  const int ty = tid >> 4;
  const int tx = tid & 15;
  const int nodeBase = blockIdx.x * 128;

  float acc[8][8];
#pragma unroll
  for (int i = 0; i < 8; ++i)
#pragma unroll
    for (int j = 0; j < 8; ++j) acc[i][j] = 0.f;

  const float* ins[3] = {x, aggL, aggG};
  const float* wts[3] = {W1, W2l, W2g};

  for (int p = 0; p < 3; ++p) {
    const float* __restrict__ A = ins[p];
    const float* __restrict__ Wp = wts[p];
    for (int kc = 0; kc < D; kc += 32) {
      __syncthreads();
#pragma unroll
      for (int i = 0; i < 4; ++i) {
        int lin = tid + i * 256;
        int r = lin >> 3;
        int q = lin & 7;
        int node = nodeBase + r;
        float4 v = make_float4(0.f, 0.f, 0.f, 0.f);
        if (node < n)
          v = *reinterpret_cast<const float4*>(A + (size_t)node * D + kc + q * 4);
        xs[r][q * 4 + 0] = v.x; xs[r][q * 4 + 1] = v.y;
        xs[r][q * 4 + 2] = v.z; xs[r][q * 4 + 3] = v.w;
        float4 w = *reinterpret_cast<const float4*>(Wp + (size_t)r * D + kc + q * 4);
        ws[r][q * 4 + 0] = w.x; ws[r][q * 4 + 1] = w.y;
        ws[r][q * 4 + 2] = w.z; ws[r][q * 4 + 3] = w.w;
      }
      __syncthreads();
#pragma unroll
      for (int k = 0; k < 32; ++k) {
        float a[8], b[8];
#pragma unroll
        for (int i = 0; i < 8; ++i) a[i] = xs[ty * 8 + i][k];
#pragma unroll
        for (int j = 0; j < 8; ++j) b[j] = ws[tx * 8 + j][k];
#pragma unroll
        for (int i = 0; i < 8; ++i)
#pragma unroll
          for (int j = 0; j < 8; ++j) acc[i][j] += a[i] * b[j];
      }
    }
  }

#pragma unroll
  for (int i = 0; i < 8; ++i) {
    int node = nodeBase + ty * 8 + i;
    if (node < n) {
      float* row = pre + (size_t)node * D + tx * 8;
      *reinterpret_cast<float4*>(row + 0) = make_float4(acc[i][0], acc[i][1], acc[i][2], acc[i][3]);
      *reinterpret_cast<float4*>(row + 4) = make_float4(acc[i][4], acc[i][5], acc[i][6], acc[i][7]);
    }
  }
}

// -------------------- BN stats --------------------
__global__ __launch_bounds__(256) void stats_kernel(
    const float* __restrict__ pre, float* __restrict__ sums,
    float* __restrict__ sumsq, int n) {
  const int f = threadIdx.x & 127;
  const int g = threadIdx.x >> 7;
  const int base = blockIdx.x * 256;
  float s = 0.f, s2 = 0.f;
  int lim = base + 256 < n ? base + 256 : n;
  for (int r = base + g; r < lim; r += 2) {
    float v = pre[(size_t)r * D + f];
    s += v;
    s2 += v * v;
  }
  __shared__ float bufs[128], bufs2[128];
  if (g) { bufs[f] = s; bufs2[f] = s2; }
  __syncthreads();
  if (!g) {
    unsafeAtomicAdd(&sums[f], s + bufs[f]);
    unsafeAtomicAdd(&sumsq[f], s2 + bufs2[f]);
  }
}

// -------------------- BN params --------------------
__global__ void bnparam_kernel(const float* __restrict__ sums,
                               const float* __restrict__ sumsq,
                               const float* __restrict__ gamma,
                               const float* __restrict__ beta,
                               float* __restrict__ scale,
                               float* __restrict__ shift, int n) {
  int f = threadIdx.x;
  float inv_n = 1.f / (float)n;
  float mean = sums[f] * inv_n;
  float var = sumsq[f] * inv_n - mean * mean;
  float sc = rsqrtf(var + BN_EPS) * gamma[f];
  scale[f] = sc;
  shift[f] = beta[f] - mean * sc;
}

// -------------------- normalize + relu (in place on d_out) --------------------
__global__ __launch_bounds__(256) void norm_relu_kernel(
    float* __restrict__ buf, const float* __restrict__ scale,
    const float* __restrict__ shift, size_t total4) {
  size_t idx = (size_t)blockIdx.x * blockDim.x + threadIdx.x;
  if (idx >= total4) return;
  size_t i = idx * 4;
  float4 v = *reinterpret_cast<const float4*>(buf + i);
  int f = (int)(i & 127);
  v.x = fmaxf(v.x * scale[f + 0] + shift[f + 0], 0.f);
  v.y = fmaxf(v.y * scale[f + 1] + shift[f + 1], 0.f);
  v.z = fmaxf(v.z * scale[f + 2] + shift[f + 2], 0.f);
  v.w = fmaxf(v.w * scale[f + 3] + shift[f + 3], 0.f);
  *reinterpret_cast<float4*>(buf + i) = v;
}

extern "C" void kernel_launch(void* const* d_in, const int* in_sizes, int n_in,
                              void* d_out, int out_size, void* d_ws, size_t ws_size,
                              hipStream_t stream) {
  const float* x     = (const float*)d_in[0];
  const int*   eiL   = (const int*)d_in[1];
  const int*   eiG   = (const int*)d_in[2];
  const float* W1    = (const float*)d_in[3];
  const float* W2l   = (const float*)d_in[4];
  const float* W2g   = (const float*)d_in[5];
  const float* gamma = (const float*)d_in[6];
  const float* beta  = (const float*)d_in[7];

  const int n = in_sizes[0] / D;        // 50000
  const int E = in_sizes[1] / 2;        // 1600000
  const size_t nd = (size_t)n * D;

  float* ws    = (float*)d_ws;
  float* aggL  = ws;                    // nd floats
  float* aggG  = ws + nd;               // nd floats
  float* sums  = ws + 2 * nd;           // 128
  float* sumsq = sums + 128;
  float* scale = sums + 256;
  float* shift = sums + 384;
  int*   deg   = (int*)(sums + 512);    // n ints
  int*   off   = deg + n;               // n ints
  int*   csr   = off + n;               // E ints
  float* pre   = (float*)d_out;         // reuse output buffer for pre-BN activations

  const int eblk = (E + 255) / 256;
  const int gblk = ((n * 64) + 255) / 256;  // one wave (64 lanes) per node

  hipMemsetAsync(sums, 0, 256 * sizeof(float), stream);

  // ---- local edge set ----
  hipMemsetAsync(deg, 0, n * sizeof(int), stream);
  hist_kernel<<<eblk, 256, 0, stream>>>(eiL, deg, E);
  scan_kernel<<<1, 1024, 0, stream>>>(deg, off, n);
  fill_kernel<<<eblk, 256, 0, stream>>>(eiL, off, csr, E);
  gather_kernel<<<gblk, 256, 0, stream>>>(x, csr, off, deg, aggL, n);

  // ---- global edge set (reuse deg/off/csr) ----
  hipMemsetAsync(deg, 0, n * sizeof(int), stream);
  hist_kernel<<<eblk, 256, 0, stream>>>(eiG, deg, E);
  scan_kernel<<<1, 1024, 0, stream>>>(deg, off, n);
  fill_kernel<<<eblk, 256, 0, stream>>>(eiG, off, csr, E);
  gather_kernel<<<gblk, 256, 0, stream>>>(x, csr, off, deg, aggG, n);

  // ---- fused 3-way GEMM into d_out ----
  gemm3_kernel<<<(n + 127) / 128, 256, 0, stream>>>(x, aggL, aggG, W1, W2l, W2g, pre, n);

  // ---- BN + ReLU ----
  stats_kernel<<<(n + 255) / 256, 256, 0, stream>>>(pre, sums, sumsq, n);
  bnparam_kernel<<<1, 128, 0, stream>>>(sums, sumsq, gamma, beta, scale, shift, n);
  {
    size_t total4 = nd / 4;
    int nblk = (int)((total4 + 255) / 256);
    norm_relu_kernel<<<nblk, 256, 0, stream>>>(pre, scale, shift, total4);
  }
}

// Round 8
// 986.065 us; speedup vs baseline: 5.7471x; 1.0744x over previous
//
#include <hip/hip_runtime.h>

#define D 128
#define BN_EPS 1e-5f

// -------------------- x -> bf16 (RNE) --------------------
__global__ __launch_bounds__(256) void convert_kernel(
    const float* __restrict__ x, ushort* __restrict__ xbf, int total8) {
  int t = blockIdx.x * 256 + threadIdx.x;
  if (t >= total8) return;
  const float4* p = reinterpret_cast<const float4*>(x) + (size_t)t * 2;
  float4 a = p[0], b = p[1];
  float v[8] = {a.x, a.y, a.z, a.w, b.x, b.y, b.z, b.w};
  uint r[8];
#pragma unroll
  for (int j = 0; j < 8; ++j) {
    uint bits = __float_as_uint(v[j]);
    r[j] = (bits + 0x7FFFu + ((bits >> 16) & 1u)) >> 16;  // round-to-nearest-even
  }
  uint4 o;
  o.x = r[0] | (r[1] << 16); o.y = r[2] | (r[3] << 16);
  o.z = r[4] | (r[5] << 16); o.w = r[6] | (r[7] << 16);
  *reinterpret_cast<uint4*>(xbf + (size_t)t * 8) = o;
}

// -------------------- CSR build: degree histogram --------------------
__global__ __launch_bounds__(256) void hist_kernel(
    const int* __restrict__ ei, int* __restrict__ deg, int E) {
  int t = blockIdx.x * blockDim.x + threadIdx.x;
  if (t < E) atomicAdd(&deg[ei[t]], 1);   // ei[0..E) = dst rows
}

// -------------------- exclusive scan of degrees (single block) --------------------
__global__ __launch_bounds__(1024) void scan_kernel(
    const int* __restrict__ deg, int* __restrict__ off, int n) {
  __shared__ int ls[1024];
  const int t = threadIdx.x;
  const int chunk = (n + 1023) / 1024;
  const int lo = t * chunk;
  const int hi = (lo + chunk < n) ? lo + chunk : n;
  int s = 0;
  for (int j = lo; j < hi; ++j) s += deg[j];
  ls[t] = s;
  __syncthreads();
  for (int d = 1; d < 1024; d <<= 1) {
    int v = (t >= d) ? ls[t - d] : 0;
    __syncthreads();
    ls[t] += v;
    __syncthreads();
  }
  int run = (t == 0) ? 0 : ls[t - 1];
  for (int j = lo; j < hi; ++j) { off[j] = run; run += deg[j]; }
}

// -------------------- CSR fill (off becomes END offsets) --------------------
__global__ __launch_bounds__(256) void fill_kernel(
    const int* __restrict__ ei, int* __restrict__ off,
    int* __restrict__ csr, int E) {
  int t = blockIdx.x * blockDim.x + threadIdx.x;
  if (t < E) {
    int dst = ei[t];
    int src = ei[E + t];
    int p = atomicAdd(&off[dst], 1);
    csr[p] = src;
  }
}

// -------------------- gather-aggregate (bf16 reads, shfl-broadcast idx) ----
// One wave per node; lane holds features [2*lane, 2*lane+1].
__global__ __launch_bounds__(256) void gather_kernel(
    const ushort* __restrict__ xbf, const int* __restrict__ csr,
    const int* __restrict__ off_end, const int* __restrict__ deg,
    float* __restrict__ agg, int n) {
  const int wid = (blockIdx.x * 256 + threadIdx.x) >> 6;
  const int lane = threadIdx.x & 63;
  if (wid >= n) return;
  const int end = off_end[wid];
  const int beg = end - deg[wid];
  float ax = 0.f, ay = 0.f;
  int e = beg;
  while (e < end) {
    int m = end - e; if (m > 64) m = 64;
    int pick = lane < m ? lane : m - 1;
    int myidx = csr[e + pick];          // one coalesced load of up to 64 indices
    int j = 0;
    for (; j + 4 <= m; j += 4) {
      int s0 = __shfl(myidx, j + 0);
      int s1 = __shfl(myidx, j + 1);
      int s2 = __shfl(myidx, j + 2);
      int s3 = __shfl(myidx, j + 3);
      uint v0 = reinterpret_cast<const uint*>(xbf + (size_t)s0 * D)[lane];
      uint v1 = reinterpret_cast<const uint*>(xbf + (size_t)s1 * D)[lane];
      uint v2 = reinterpret_cast<const uint*>(xbf + (size_t)s2 * D)[lane];
      uint v3 = reinterpret_cast<const uint*>(xbf + (size_t)s3 * D)[lane];
      ax += __uint_as_float(v0 << 16) + __uint_as_float(v1 << 16)
          + __uint_as_float(v2 << 16) + __uint_as_float(v3 << 16);
      ay += __uint_as_float(v0 & 0xFFFF0000u) + __uint_as_float(v1 & 0xFFFF0000u)
          + __uint_as_float(v2 & 0xFFFF0000u) + __uint_as_float(v3 & 0xFFFF0000u);
    }
    for (; j < m; ++j) {
      int s = __shfl(myidx, j);
      uint v = reinterpret_cast<const uint*>(xbf + (size_t)s * D)[lane];
      ax += __uint_as_float(v << 16);
      ay += __uint_as_float(v & 0xFFFF0000u);
    }
    e += m;
  }
  *reinterpret_cast<float2*>(agg + (size_t)wid * D + lane * 2) = make_float2(ax, ay);
}

// -------------------- fused 3-way GEMM, 64x128 tile, cyclic mapping --------
__global__ __launch_bounds__(256) void gemm3_kernel(
    const float* __restrict__ x, const float* __restrict__ aggL,
    const float* __restrict__ aggG, const float* __restrict__ W1,
    const float* __restrict__ W2l, const float* __restrict__ W2g,
    float* __restrict__ pre, int n) {
  __shared__ float xs[64][36];    // stride 36: rows 144B-aligned, b128 reads 2-way (free)
  __shared__ float wsh[128][36];
  const int tid = threadIdx.x;
  const int ty = tid >> 4;        // 0..15
  const int tx = tid & 15;        // 0..15
  const int nodeBase = blockIdx.x * 64;

  float acc[4][8];
#pragma unroll
  for (int i = 0; i < 4; ++i)
#pragma unroll
    for (int j = 0; j < 8; ++j) acc[i][j] = 0.f;

  const float* ins[3] = {x, aggL, aggG};
  const float* wts[3] = {W1, W2l, W2g};

  for (int p = 0; p < 3; ++p) {
    const float* __restrict__ A = ins[p];
    const float* __restrict__ Wp = wts[p];
    for (int kc = 0; kc < D; kc += 32) {
      __syncthreads();
      // A tile 64x32: 2 float4 per thread
#pragma unroll
      for (int i = 0; i < 2; ++i) {
        int lin = tid + i * 256;       // 0..511
        int r = lin >> 3, q = lin & 7;
        int node = nodeBase + r;
        float4 v = make_float4(0.f, 0.f, 0.f, 0.f);
        if (node < n)
          v = *reinterpret_cast<const float4*>(A + (size_t)node * D + kc + q * 4);
        *reinterpret_cast<float4*>(&xs[r][q * 4]) = v;
      }
      // W tile 128x32: 4 float4 per thread
#pragma unroll
      for (int i = 0; i < 4; ++i) {
        int lin = tid + i * 256;       // 0..1023
        int r = lin >> 3, q = lin & 7;
        *reinterpret_cast<float4*>(&wsh[r][q * 4]) =
            *reinterpret_cast<const float4*>(Wp + (size_t)r * D + kc + q * 4);
      }
      __syncthreads();
#pragma unroll
      for (int k = 0; k < 32; k += 4) {
        float4 a4[4], b4[8];
#pragma unroll
        for (int i = 0; i < 4; ++i) a4[i] = *reinterpret_cast<const float4*>(&xs[ty + 16 * i][k]);
#pragma unroll
        for (int j = 0; j < 8; ++j) b4[j] = *reinterpret_cast<const float4*>(&wsh[tx + 16 * j][k]);
#pragma unroll
        for (int i = 0; i < 4; ++i)
#pragma unroll
          for (int j = 0; j < 8; ++j)
            acc[i][j] += a4[i].x * b4[j].x + a4[i].y * b4[j].y +
                         a4[i].z * b4[j].z + a4[i].w * b4[j].w;
      }
    }
  }

#pragma unroll
  for (int i = 0; i < 4; ++i) {
    int node = nodeBase + ty + 16 * i;
    if (node < n) {
#pragma unroll
      for (int j = 0; j < 8; ++j)
        pre[(size_t)node * D + tx + 16 * j] = acc[i][j];
    }
  }
}

// -------------------- BN stats --------------------
__global__ __launch_bounds__(256) void stats_kernel(
    const float* __restrict__ pre, float* __restrict__ sums,
    float* __restrict__ sumsq, int n) {
  const int f = threadIdx.x & 127;
  const int g = threadIdx.x >> 7;
  const int base = blockIdx.x * 256;
  float s = 0.f, s2 = 0.f;
  int lim = base + 256 < n ? base + 256 : n;
  for (int r = base + g; r < lim; r += 2) {
    float v = pre[(size_t)r * D + f];
    s += v;
    s2 += v * v;
  }
  __shared__ float bufs[128], bufs2[128];
  if (g) { bufs[f] = s; bufs2[f] = s2; }
  __syncthreads();
  if (!g) {
    unsafeAtomicAdd(&sums[f], s + bufs[f]);
    unsafeAtomicAdd(&sumsq[f], s2 + bufs2[f]);
  }
}

// -------------------- BN params --------------------
__global__ void bnparam_kernel(const float* __restrict__ sums,
                               const float* __restrict__ sumsq,
                               const float* __restrict__ gamma,
                               const float* __restrict__ beta,
                               float* __restrict__ scale,
                               float* __restrict__ shift, int n) {
  int f = threadIdx.x;
  float inv_n = 1.f / (float)n;
  float mean = sums[f] * inv_n;
  float var = sumsq[f] * inv_n - mean * mean;
  float sc = rsqrtf(var + BN_EPS) * gamma[f];
  scale[f] = sc;
  shift[f] = beta[f] - mean * sc;
}

// -------------------- normalize + relu (in place on d_out) --------------------
__global__ __launch_bounds__(256) void norm_relu_kernel(
    float* __restrict__ buf, const float* __restrict__ scale,
    const float* __restrict__ shift, size_t total4) {
  size_t idx = (size_t)blockIdx.x * blockDim.x + threadIdx.x;
  if (idx >= total4) return;
  size_t i = idx * 4;
  float4 v = *reinterpret_cast<const float4*>(buf + i);
  int f = (int)(i & 127);
  v.x = fmaxf(v.x * scale[f + 0] + shift[f + 0], 0.f);
  v.y = fmaxf(v.y * scale[f + 1] + shift[f + 1], 0.f);
  v.z = fmaxf(v.z * scale[f + 2] + shift[f + 2], 0.f);
  v.w = fmaxf(v.w * scale[f + 3] + shift[f + 3], 0.f);
  *reinterpret_cast<float4*>(buf + i) = v;
}

extern "C" void kernel_launch(void* const* d_in, const int* in_sizes, int n_in,
                              void* d_out, int out_size, void* d_ws, size_t ws_size,
                              hipStream_t stream) {
  const float* x     = (const float*)d_in[0];
  const int*   eiL   = (const int*)d_in[1];
  const int*   eiG   = (const int*)d_in[2];
  const float* W1    = (const float*)d_in[3];
  const float* W2l   = (const float*)d_in[4];
  const float* W2g   = (const float*)d_in[5];
  const float* gamma = (const float*)d_in[6];
  const float* beta  = (const float*)d_in[7];

  const int n = in_sizes[0] / D;        // 50000
  const int E = in_sizes[1] / 2;        // 1600000
  const size_t nd = (size_t)n * D;

  float* ws    = (float*)d_ws;
  float* aggL  = ws;                    // nd floats
  float* aggG  = ws + nd;               // nd floats
  float* sums  = ws + 2 * nd;           // 128
  float* sumsq = sums + 128;
  float* scale = sums + 256;
  float* shift = sums + 384;
  int*   deg   = (int*)(sums + 512);    // n ints
  int*   off   = deg + n;               // n ints
  int*   csr   = off + n;               // E ints
  ushort* xbf  = (ushort*)(csr + E);    // nd bf16
  float* pre   = (float*)d_out;         // pre-BN activations live in d_out

  const int eblk = (E + 255) / 256;
  const int gblk = ((n * 64) + 255) / 256;  // one wave per node

  convert_kernel<<<((int)(nd / 8) + 255) / 256, 256, 0, stream>>>(x, xbf, (int)(nd / 8));
  hipMemsetAsync(sums, 0, 256 * sizeof(float), stream);

  // ---- local edge set ----
  hipMemsetAsync(deg, 0, n * sizeof(int), stream);
  hist_kernel<<<eblk, 256, 0, stream>>>(eiL, deg, E);
  scan_kernel<<<1, 1024, 0, stream>>>(deg, off, n);
  fill_kernel<<<eblk, 256, 0, stream>>>(eiL, off, csr, E);
  gather_kernel<<<gblk, 256, 0, stream>>>(xbf, csr, off, deg, aggL, n);

  // ---- global edge set (reuse deg/off/csr) ----
  hipMemsetAsync(deg, 0, n * sizeof(int), stream);
  hist_kernel<<<eblk, 256, 0, stream>>>(eiG, deg, E);
  scan_kernel<<<1, 1024, 0, stream>>>(deg, off, n);
  fill_kernel<<<eblk, 256, 0, stream>>>(eiG, off, csr, E);
  gather_kernel<<<gblk, 256, 0, stream>>>(xbf, csr, off, deg, aggG, n);

  // ---- fused 3-way GEMM into d_out ----
  gemm3_kernel<<<(n + 63) / 64, 256, 0, stream>>>(x, aggL, aggG, W1, W2l, W2g, pre, n);

  // ---- BN + ReLU ----
  stats_kernel<<<(n + 255) / 256, 256, 0, stream>>>(pre, sums, sumsq, n);
  bnparam_kernel<<<1, 128, 0, stream>>>(sums, sumsq, gamma, beta, scale, shift, n);
  {
    size_t total4 = nd / 4;
    int nblk = (int)((total4 + 255) / 256);
    norm_relu_kernel<<<nblk, 256, 0, stream>>>(pre, scale, shift, total4);
  }
}

// Round 14
// 793.321 us; speedup vs baseline: 7.1435x; 1.2430x over previous
//
#include <hip/hip_runtime.h>

#define D 128
#define BN_EPS 1e-5f

typedef float f32x4 __attribute__((ext_vector_type(4)));
typedef short bf16x8 __attribute__((ext_vector_type(8)));

// -------------------- f32 -> bf16 (RNE), 8 elems/thread --------------------
__global__ __launch_bounds__(256) void convert_kernel(
    const float* __restrict__ x, ushort* __restrict__ xbf, int total8) {
  int t = blockIdx.x * 256 + threadIdx.x;
  if (t >= total8) return;
  const float4* p = reinterpret_cast<const float4*>(x) + (size_t)t * 2;
  float4 a = p[0], b = p[1];
  float v[8] = {a.x, a.y, a.z, a.w, b.x, b.y, b.z, b.w};
  uint r[8];
#pragma unroll
  for (int j = 0; j < 8; ++j) {
    uint bits = __float_as_uint(v[j]);
    r[j] = (bits + 0x7FFFu + ((bits >> 16) & 1u)) >> 16;  // round-to-nearest-even
  }
  uint4 o;
  o.x = r[0] | (r[1] << 16); o.y = r[2] | (r[3] << 16);
  o.z = r[4] | (r[5] << 16); o.w = r[6] | (r[7] << 16);
  *reinterpret_cast<uint4*>(xbf + (size_t)t * 8) = o;
}

// -------------------- CSR build: degree histogram --------------------
__global__ __launch_bounds__(256) void hist_kernel(
    const int* __restrict__ ei, int* __restrict__ deg, int E) {
  int t = blockIdx.x * blockDim.x + threadIdx.x;
  if (t < E) atomicAdd(&deg[ei[t]], 1);   // ei[0..E) = dst rows
}

// -------------------- exclusive scan of degrees (single block) --------------------
__global__ __launch_bounds__(1024) void scan_kernel(
    const int* __restrict__ deg, int* __restrict__ off, int n) {
  __shared__ int ls[1024];
  const int t = threadIdx.x;
  const int chunk = (n + 1023) / 1024;
  const int lo = t * chunk;
  const int hi = (lo + chunk < n) ? lo + chunk : n;
  int s = 0;
  for (int j = lo; j < hi; ++j) s += deg[j];
  ls[t] = s;
  __syncthreads();
  for (int d = 1; d < 1024; d <<= 1) {
    int v = (t >= d) ? ls[t - d] : 0;
    __syncthreads();
    ls[t] += v;
    __syncthreads();
  }
  int run = (t == 0) ? 0 : ls[t - 1];
  for (int j = lo; j < hi; ++j) { off[j] = run; run += deg[j]; }
}

// -------------------- CSR fill (off becomes END offsets) --------------------
__global__ __launch_bounds__(256) void fill_kernel(
    const int* __restrict__ ei, int* __restrict__ off,
    int* __restrict__ csr, int E) {
  int t = blockIdx.x * blockDim.x + threadIdx.x;
  if (t < E) {
    int dst = ei[t];
    int src = ei[E + t];
    int p = atomicAdd(&off[dst], 1);
    csr[p] = src;
  }
}

// -------------------- gather-aggregate: f32 accum, bf16 out --------------------
// One wave per node; lane holds features [2*lane, 2*lane+1].
__global__ __launch_bounds__(256) void gather_kernel(
    const ushort* __restrict__ xbf, const int* __restrict__ csr,
    const int* __restrict__ off_end, const int* __restrict__ deg,
    ushort* __restrict__ agg, int n) {
  const int wid = (blockIdx.x * 256 + threadIdx.x) >> 6;
  const int lane = threadIdx.x & 63;
  if (wid >= n) return;
  const int end = off_end[wid];
  const int beg = end - deg[wid];
  float ax = 0.f, ay = 0.f;
  int e = beg;
  while (e < end) {
    int m = end - e; if (m > 64) m = 64;
    int pick = lane < m ? lane : m - 1;
    int myidx = csr[e + pick];          // one coalesced load of up to 64 indices
    int j = 0;
    for (; j + 4 <= m; j += 4) {
      int s0 = __shfl(myidx, j + 0);
      int s1 = __shfl(myidx, j + 1);
      int s2 = __shfl(myidx, j + 2);
      int s3 = __shfl(myidx, j + 3);
      uint v0 = reinterpret_cast<const uint*>(xbf + (size_t)s0 * D)[lane];
      uint v1 = reinterpret_cast<const uint*>(xbf + (size_t)s1 * D)[lane];
      uint v2 = reinterpret_cast<const uint*>(xbf + (size_t)s2 * D)[lane];
      uint v3 = reinterpret_cast<const uint*>(xbf + (size_t)s3 * D)[lane];
      ax += __uint_as_float(v0 << 16) + __uint_as_float(v1 << 16)
          + __uint_as_float(v2 << 16) + __uint_as_float(v3 << 16);
      ay += __uint_as_float(v0 & 0xFFFF0000u) + __uint_as_float(v1 & 0xFFFF0000u)
          + __uint_as_float(v2 & 0xFFFF0000u) + __uint_as_float(v3 & 0xFFFF0000u);
    }
    for (; j < m; ++j) {
      int s = __shfl(myidx, j);
      uint v = reinterpret_cast<const uint*>(xbf + (size_t)s * D)[lane];
      ax += __uint_as_float(v << 16);
      ay += __uint_as_float(v & 0xFFFF0000u);
    }
    e += m;
  }
  uint bx = __float_as_uint(ax);
  uint by = __float_as_uint(ay);
  uint rx = (bx + 0x7FFFu + ((bx >> 16) & 1u)) >> 16;
  uint ry = (by + 0x7FFFu + ((by >> 16) & 1u)) >> 16;
  reinterpret_cast<uint*>(agg)[(size_t)wid * 64 + lane] = rx | (ry << 16);
}

// -------------------- MFMA 3-way GEMM: pre = [x|aggL|aggG] @ [W1|W2l|W2g]^T
// Tile 128x128, 4 waves (2x2), mfma_f32_16x16x32_bf16, LDS rows padded to 40.
__global__ __launch_bounds__(256) void gemm3_mfma(
    const ushort* __restrict__ xbf, const ushort* __restrict__ aggLb,
    const ushort* __restrict__ aggGb, const ushort* __restrict__ Wb,
    float* __restrict__ pre, int n) {
  __shared__ ushort As[128][40];   // 32 k-cols + pad; row stride 80B (2-way, free)
  __shared__ ushort Bs[128][40];
  const int tid = threadIdx.x;
  const int wave = tid >> 6, lane = tid & 63;
  const int wm = wave >> 1, wn = wave & 1;    // 2x2 wave grid, 64x64 each
  const int rowBase = blockIdx.x * 128;
  const int l15 = lane & 15, lhi8 = (lane >> 4) * 8;

  f32x4 acc[4][4];
#pragma unroll
  for (int i = 0; i < 4; ++i)
#pragma unroll
    for (int j = 0; j < 4; ++j) acc[i][j] = (f32x4)(0.f);

  for (int p = 0; p < 3; ++p) {
    const ushort* __restrict__ A = (p == 0) ? xbf : (p == 1 ? aggLb : aggGb);
    const ushort* __restrict__ W = Wb + p * 16384;
    for (int kc = 0; kc < D; kc += 32) {
      __syncthreads();
      // stage A,B tiles: 128 rows x 32 bf16 = 512 16B-chunks each, 2/thread
#pragma unroll
      for (int i = 0; i < 2; ++i) {
        int c = tid + i * 256;          // 0..511
        int r = c >> 2, q = (c & 3) * 8;
        int node = rowBase + r;
        uint4 va = make_uint4(0, 0, 0, 0);
        if (node < n)
          va = *reinterpret_cast<const uint4*>(A + (size_t)node * D + kc + q);
        *reinterpret_cast<uint4*>(&As[r][q]) = va;
        *reinterpret_cast<uint4*>(&Bs[r][q]) =
            *reinterpret_cast<const uint4*>(W + (size_t)r * D + kc + q);
      }
      __syncthreads();
      bf16x8 af[4], bf[4];
#pragma unroll
      for (int mi = 0; mi < 4; ++mi)
        af[mi] = *reinterpret_cast<const bf16x8*>(&As[wm * 64 + mi * 16 + l15][lhi8]);
#pragma unroll
      for (int ni = 0; ni < 4; ++ni)
        bf[ni] = *reinterpret_cast<const bf16x8*>(&Bs[wn * 64 + ni * 16 + l15][lhi8]);
#pragma unroll
      for (int mi = 0; mi < 4; ++mi)
#pragma unroll
        for (int ni = 0; ni < 4; ++ni)
          acc[mi][ni] = __builtin_amdgcn_mfma_f32_16x16x32_bf16(
              af[mi], bf[ni], acc[mi][ni], 0, 0, 0);
    }
  }

  // store: C/D layout col=l&15, row=(l>>4)*4+j  [m89-verified]
#pragma unroll
  for (int mi = 0; mi < 4; ++mi) {
#pragma unroll
    for (int j = 0; j < 4; ++j) {
      int row = rowBase + wm * 64 + mi * 16 + (lane >> 4) * 4 + j;
      if (row < n) {
        float* o = pre + (size_t)row * D + wn * 64 + l15;
#pragma unroll
        for (int ni = 0; ni < 4; ++ni) o[ni * 16] = acc[mi][ni][j];
      }
    }
  }
}

// -------------------- BN stats --------------------
__global__ __launch_bounds__(256) void stats_kernel(
    const float* __restrict__ pre, float* __restrict__ sums,
    float* __restrict__ sumsq, int n) {
  const int f = threadIdx.x & 127;
  const int g = threadIdx.x >> 7;
  const int base = blockIdx.x * 256;
  float s = 0.f, s2 = 0.f;
  int lim = base + 256 < n ? base + 256 : n;
  for (int r = base + g; r < lim; r += 2) {
    float v = pre[(size_t)r * D + f];
    s += v;
    s2 += v * v;
  }
  __shared__ float bufs[128], bufs2[128];
  if (g) { bufs[f] = s; bufs2[f] = s2; }
  __syncthreads();
  if (!g) {
    unsafeAtomicAdd(&sums[f], s + bufs[f]);
    unsafeAtomicAdd(&sumsq[f], s2 + bufs2[f]);
  }
}

// -------------------- BN params --------------------
__global__ void bnparam_kernel(const float* __restrict__ sums,
                               const float* __restrict__ sumsq,
                               const float* __restrict__ gamma,
                               const float* __restrict__ beta,
                               float* __restrict__ scale,
                               float* __restrict__ shift, int n) {
  int f = threadIdx.x;
  float inv_n = 1.f / (float)n;
  float mean = sums[f] * inv_n;
  float var = sumsq[f] * inv_n - mean * mean;
  float sc = rsqrtf(var + BN_EPS) * gamma[f];
  scale[f] = sc;
  shift[f] = beta[f] - mean * sc;
}

// -------------------- normalize + relu (in place on d_out) --------------------
__global__ __launch_bounds__(256) void norm_relu_kernel(
    float* __restrict__ buf, const float* __restrict__ scale,
    const float* __restrict__ shift, size_t total4) {
  size_t idx = (size_t)blockIdx.x * blockDim.x + threadIdx.x;
  if (idx >= total4) return;
  size_t i = idx * 4;
  float4 v = *reinterpret_cast<const float4*>(buf + i);
  int f = (int)(i & 127);
  v.x = fmaxf(v.x * scale[f + 0] + shift[f + 0], 0.f);
  v.y = fmaxf(v.y * scale[f + 1] + shift[f + 1], 0.f);
  v.z = fmaxf(v.z * scale[f + 2] + shift[f + 2], 0.f);
  v.w = fmaxf(v.w * scale[f + 3] + shift[f + 3], 0.f);
  *reinterpret_cast<float4*>(buf + i) = v;
}

extern "C" void kernel_launch(void* const* d_in, const int* in_sizes, int n_in,
                              void* d_out, int out_size, void* d_ws, size_t ws_size,
                              hipStream_t stream) {
  const float* x     = (const float*)d_in[0];
  const int*   eiL   = (const int*)d_in[1];
  const int*   eiG   = (const int*)d_in[2];
  const float* W1    = (const float*)d_in[3];
  const float* W2l   = (const float*)d_in[4];
  const float* W2g   = (const float*)d_in[5];
  const float* gamma = (const float*)d_in[6];
  const float* beta  = (const float*)d_in[7];

  const int n = in_sizes[0] / D;        // 50000
  const int E = in_sizes[1] / 2;        // 1600000
  const size_t nd = (size_t)n * D;

  float* ws    = (float*)d_ws;
  float* sums  = ws;                    // 128
  float* sumsq = sums + 128;
  float* scale = sums + 256;
  float* shift = sums + 384;
  int*   deg   = (int*)(sums + 512);    // n ints
  int*   off   = deg + n;               // n ints
  int*   csr   = off + n;               // E ints
  ushort* xbf   = (ushort*)(csr + E);   // nd bf16
  ushort* aggLb = xbf + nd;             // nd bf16
  ushort* aggGb = aggLb + nd;           // nd bf16
  ushort* Wb    = aggGb + nd;           // 3*128*128 bf16
  float* pre   = (float*)d_out;         // pre-BN activations live in d_out

  const int eblk = (E + 255) / 256;
  const int gblk = ((n * 64) + 255) / 256;  // one wave per node

  // ---- bf16 conversions: x and the three weight matrices ----
  convert_kernel<<<((int)(nd / 8) + 255) / 256, 256, 0, stream>>>(x, xbf, (int)(nd / 8));
  convert_kernel<<<8, 256, 0, stream>>>(W1,  Wb,          2048);
  convert_kernel<<<8, 256, 0, stream>>>(W2l, Wb + 16384,  2048);
  convert_kernel<<<8, 256, 0, stream>>>(W2g, Wb + 32768,  2048);
  hipMemsetAsync(sums, 0, 256 * sizeof(float), stream);

  // ---- local edge set ----
  hipMemsetAsync(deg, 0, n * sizeof(int), stream);
  hist_kernel<<<eblk, 256, 0, stream>>>(eiL, deg, E);
  scan_kernel<<<1, 1024, 0, stream>>>(deg, off, n);
  fill_kernel<<<eblk, 256, 0, stream>>>(eiL, off, csr, E);
  gather_kernel<<<gblk, 256, 0, stream>>>(xbf, csr, off, deg, aggLb, n);

  // ---- global edge set (reuse deg/off/csr) ----
  hipMemsetAsync(deg, 0, n * sizeof(int), stream);
  hist_kernel<<<eblk, 256, 0, stream>>>(eiG, deg, E);
  scan_kernel<<<1, 1024, 0, stream>>>(deg, off, n);
  fill_kernel<<<eblk, 256, 0, stream>>>(eiG, off, csr, E);
  gather_kernel<<<gblk, 256, 0, stream>>>(xbf, csr, off, deg, aggGb, n);

  // ---- MFMA 3-way GEMM into d_out ----
  gemm3_mfma<<<(n + 127) / 128, 256, 0, stream>>>(xbf, aggLb, aggGb, Wb, pre, n);

  // ---- BN + ReLU ----
  stats_kernel<<<(n + 255) / 256, 256, 0, stream>>>(pre, sums, sumsq, n);
  bnparam_kernel<<<1, 128, 0, stream>>>(sums, sumsq, gamma, beta, scale, shift, n);
  {
    size_t total4 = nd / 4;
    int nblk = (int)((total4 + 255) / 256);
    norm_relu_kernel<<<nblk, 256, 0, stream>>>(pre, scale, shift, total4);
  }
}